// Round 1
// baseline (373.730 us; speedup 1.0000x reference)
//
#include <hip/hip_runtime.h>

// VectorQuantizer on MI355X.
// z: [32,256,32,32] fp32  (B=32,C=256,H=32,W=32; N = B*H*W = 32768 tokens)
// codebook: [1024,256] fp32 (K=1024)
// out: [8388608 floats z_q_st] ++ [vq_loss] ++ [perplexity]
//
// token n = b*1024 + hw; z_flat[n][c] = z[b*262144 + c*1024 + hw]
// -> for a block of 64 consecutive n (same b, contiguous hw), element (t,c)
//    sits at zb + c*1024 + t : coalesced along t.
//
// ws layout (bytes):
//   cbT    @ 0        : float[256][1024]  (1 MB)   codebook transposed
//   enorm  @ 1048576  : float[1024]                |e_k|^2
//   idx    @ 1052672  : int[32768]                 argmin indices
//   counts @ 1183744  : int[1024]                  histogram
//   lsum   @ 1187840  : float[1]                   sum of (z_q - z)^2

#define BETA 0.25f

// ---------------------------------------------------------------------------
// Kernel 1: transpose codebook + row norms + zero accumulators. grid=256x256.
// wave w of block b handles codebook row r = b*4+w; 64 lanes x float4 = 256 c.
// ---------------------------------------------------------------------------
__global__ __launch_bounds__(256) void vq_prep(
    const float* __restrict__ cb, float* __restrict__ cbT,
    float* __restrict__ enorm, int* __restrict__ counts,
    float* __restrict__ lsum)
{
    const int tid = threadIdx.x;
    if (blockIdx.x < 4) counts[blockIdx.x * 256 + tid] = 0;
    if (blockIdx.x == 4 && tid == 0) *lsum = 0.0f;

    const int lane = tid & 63;
    const int wid  = tid >> 6;
    const int r    = blockIdx.x * 4 + wid;            // 0..1023
    const float4 v = *reinterpret_cast<const float4*>(cb + r * 256 + lane * 4);
    const int c = lane * 4;
    cbT[(c + 0) * 1024 + r] = v.x;
    cbT[(c + 1) * 1024 + r] = v.y;
    cbT[(c + 2) * 1024 + r] = v.z;
    cbT[(c + 3) * 1024 + r] = v.w;
    float s = v.x * v.x + v.y * v.y + v.z * v.z + v.w * v.w;
    #pragma unroll
    for (int off = 32; off > 0; off >>= 1) s += __shfl_down(s, off);
    if (lane == 0) enorm[r] = s;
}

// ---------------------------------------------------------------------------
// Kernel 2: fused distance-GEMM + argmin. grid=512, block=256 (16x16 threads,
// 4x4 microtile). 64 tokens/block, k-tiles of 64, c-chunks of 32.
// dist = |e|^2 - 2 * z.e   (|z|^2 dropped: argmin-invariant)
// LDS: zs[256][68] (z tile, [c][t]) + es[32][68] (codebook chunk, [c][k])
//      = 78336 B -> 2 blocks/CU.
// ---------------------------------------------------------------------------
__global__ __launch_bounds__(256, 2) void vq_argmin(
    const float* __restrict__ z, const float* __restrict__ cbT,
    const float* __restrict__ enorm, int* __restrict__ idx_out)
{
    __shared__ float zs[256 * 68];
    __shared__ float es[32 * 68];
    const int tid = threadIdx.x;
    const int n0  = blockIdx.x * 64;
    const float* zb = z + (n0 >> 10) * 262144 + (n0 & 1023);

    // stage z tile: [64 t x 256 c] -> zs[c][t]; float4 along t, coalesced.
    {
        const int tt4  = (tid & 15) << 2;
        const int crow = tid >> 4;
        #pragma unroll
        for (int it = 0; it < 16; ++it) {
            const int c = it * 16 + crow;
            *reinterpret_cast<float4*>(&zs[c * 68 + tt4]) =
                *reinterpret_cast<const float4*>(zb + c * 1024 + tt4);
        }
    }

    const int i4 = (tid & 15) << 2;   // token sub-base (4 tokens)
    const int j  = tid >> 4;          // k-group 0..15
    const int j4 = j << 2;

    float minv[4] = {1e30f, 1e30f, 1e30f, 1e30f};
    int   mini[4] = {0, 0, 0, 0};

    for (int kt = 0; kt < 16; ++kt) {
        float acc[4][4] = {};
        for (int cch = 0; cch < 8; ++cch) {
            __syncthreads();
            {   // stage codebook chunk: cbT rows [cch*32, +32), cols [kt*64, +64)
                const int k4 = (tid & 15) << 2;
                const int cr = tid >> 4;
                const float* src = cbT + (cch * 32 + cr) * 1024 + kt * 64 + k4;
                *reinterpret_cast<float4*>(&es[cr * 68 + k4]) =
                    *reinterpret_cast<const float4*>(src);
                *reinterpret_cast<float4*>(&es[(cr + 16) * 68 + k4]) =
                    *reinterpret_cast<const float4*>(src + 16 * 1024);
            }
            __syncthreads();
            const int czoff = cch * 32;
            #pragma unroll 8
            for (int cc = 0; cc < 32; ++cc) {
                const float4 zf = *reinterpret_cast<const float4*>(&zs[(czoff + cc) * 68 + i4]);
                const float4 ef = *reinterpret_cast<const float4*>(&es[cc * 68 + j4]);
                acc[0][0] = fmaf(zf.x, ef.x, acc[0][0]);
                acc[0][1] = fmaf(zf.x, ef.y, acc[0][1]);
                acc[0][2] = fmaf(zf.x, ef.z, acc[0][2]);
                acc[0][3] = fmaf(zf.x, ef.w, acc[0][3]);
                acc[1][0] = fmaf(zf.y, ef.x, acc[1][0]);
                acc[1][1] = fmaf(zf.y, ef.y, acc[1][1]);
                acc[1][2] = fmaf(zf.y, ef.z, acc[1][2]);
                acc[1][3] = fmaf(zf.y, ef.w, acc[1][3]);
                acc[2][0] = fmaf(zf.z, ef.x, acc[2][0]);
                acc[2][1] = fmaf(zf.z, ef.y, acc[2][1]);
                acc[2][2] = fmaf(zf.z, ef.z, acc[2][2]);
                acc[2][3] = fmaf(zf.z, ef.w, acc[2][3]);
                acc[3][0] = fmaf(zf.w, ef.x, acc[3][0]);
                acc[3][1] = fmaf(zf.w, ef.y, acc[3][1]);
                acc[3][2] = fmaf(zf.w, ef.z, acc[3][2]);
                acc[3][3] = fmaf(zf.w, ef.w, acc[3][3]);
            }
        }
        const int kbase = kt * 64 + j4;
        const float4 en = *reinterpret_cast<const float4*>(enorm + kbase);
        #pragma unroll
        for (int ti = 0; ti < 4; ++ti) {
            const float d0 = en.x - 2.0f * acc[ti][0];
            const float d1 = en.y - 2.0f * acc[ti][1];
            const float d2 = en.z - 2.0f * acc[ti][2];
            const float d3 = en.w - 2.0f * acc[ti][3];
            // ascending k with strict < keeps first-occurrence (jnp.argmin) ties
            if (d0 < minv[ti]) { minv[ti] = d0; mini[ti] = kbase + 0; }
            if (d1 < minv[ti]) { minv[ti] = d1; mini[ti] = kbase + 1; }
            if (d2 < minv[ti]) { minv[ti] = d2; mini[ti] = kbase + 2; }
            if (d3 < minv[ti]) { minv[ti] = d3; mini[ti] = kbase + 3; }
        }
    }

    // cross-thread reduce: 16 candidates per token (reuse zs as scratch)
    __syncthreads();
    float* rv = zs;                                   // [64][16] vals
    int*   ri = reinterpret_cast<int*>(zs) + 1024;    // [64][16] idxs
    #pragma unroll
    for (int ti = 0; ti < 4; ++ti) {
        const int t = i4 + ti;
        rv[t * 16 + j] = minv[ti];
        ri[t * 16 + j] = mini[ti];
    }
    __syncthreads();
    if (tid < 64) {
        float bv = rv[tid * 16];
        int   bi = ri[tid * 16];
        #pragma unroll
        for (int jj = 1; jj < 16; ++jj) {
            const float v  = rv[tid * 16 + jj];
            const int   ii = ri[tid * 16 + jj];
            if (v < bv || (v == bv && ii < bi)) { bv = v; bi = ii; }
        }
        idx_out[n0 + tid] = bi;
    }
}

// ---------------------------------------------------------------------------
// Kernel 3: gather z_q -> out (z_q_st forward value == z_q), fused
// sum((z_q - z)^2) and code-usage histogram. grid=512, block=256.
// ---------------------------------------------------------------------------
__global__ __launch_bounds__(256) void vq_epilogue(
    const float* __restrict__ z, const float* __restrict__ cb,
    const int* __restrict__ idx, float* __restrict__ out,
    int* __restrict__ counts, float* __restrict__ lsum)
{
    __shared__ int   sidx[64];
    __shared__ float swsum[4];
    const int tid = threadIdx.x;
    const int n0  = blockIdx.x * 64;
    if (tid < 64) {
        const int ii = idx[n0 + tid];
        sidx[tid] = ii;
        atomicAdd(&counts[ii], 1);
    }
    __syncthreads();
    const float* zb = z   + (n0 >> 10) * 262144 + (n0 & 1023);
    float*       ob = out + (n0 >> 10) * 262144 + (n0 & 1023);
    const int t  = tid & 63;
    const int cg = tid >> 6;
    const int row = sidx[t] << 8;   // * 256
    float sum = 0.0f;
    for (int c = cg; c < 256; c += 4) {
        const float q  = cb[row + c];        // gather, L2-resident (1 MB)
        const float zv = zb[c * 1024 + t];   // coalesced
        const float d  = q - zv;
        sum = fmaf(d, d, sum);
        ob[c * 1024 + t] = q;                // coalesced
    }
    #pragma unroll
    for (int off = 32; off > 0; off >>= 1) sum += __shfl_down(sum, off);
    if ((tid & 63) == 0) swsum[tid >> 6] = sum;
    __syncthreads();
    if (tid == 0) atomicAdd(lsum, swsum[0] + swsum[1] + swsum[2] + swsum[3]);
}

// ---------------------------------------------------------------------------
// Kernel 4: scalars. vq_loss = (1+BETA)*MSE; perplexity = exp(-sum p ln p).
// ---------------------------------------------------------------------------
__global__ __launch_bounds__(256) void vq_finalize(
    const int* __restrict__ counts, const float* __restrict__ lsum,
    float* __restrict__ outs)
{
    __shared__ float ssum[4];
    const int tid = threadIdx.x;
    float local = 0.0f;
    #pragma unroll
    for (int k = tid; k < 1024; k += 256) {
        float p = (float)counts[k] * (1.0f / 32768.0f);
        p = fmaxf(p, 1e-10f);               // jnp.clip(probs, EPS)
        local += p * logf(p);
    }
    #pragma unroll
    for (int off = 32; off > 0; off >>= 1) local += __shfl_down(local, off);
    if ((tid & 63) == 0) ssum[tid >> 6] = local;
    __syncthreads();
    if (tid == 0) {
        const float ent = ssum[0] + ssum[1] + ssum[2] + ssum[3]; // sum p ln p (<=0)
        outs[0] = lsum[0] * ((1.0f + BETA) / 8388608.0f);
        outs[1] = expf(-ent);
    }
}

extern "C" void kernel_launch(void* const* d_in, const int* in_sizes, int n_in,
                              void* d_out, int out_size, void* d_ws, size_t ws_size,
                              hipStream_t stream)
{
    const float* z  = (const float*)d_in[0];
    const float* cb = (const float*)d_in[1];
    float* out = (float*)d_out;
    char*  ws  = (char*)d_ws;
    float* cbT    = (float*)(ws);
    float* enorm  = (float*)(ws + 1048576);
    int*   idx    = (int*)  (ws + 1052672);
    int*   counts = (int*)  (ws + 1183744);
    float* lsum   = (float*)(ws + 1187840);

    vq_prep    <<<256, 256, 0, stream>>>(cb, cbT, enorm, counts, lsum);
    vq_argmin  <<<512, 256, 0, stream>>>(z, cbT, enorm, idx);
    vq_epilogue<<<512, 256, 0, stream>>>(z, cb, idx, out, counts, lsum);
    vq_finalize<<<1,   256, 0, stream>>>(counts, lsum, out + 8388608);
}

// Round 2
// 277.101 us; speedup vs baseline: 1.3487x; 1.3487x over previous
//
#include <hip/hip_runtime.h>

// VectorQuantizer on MI355X — round 2: f16-split MFMA distance GEMM.
// z: [32,256,32,32] fp32; codebook: [1024,256] fp32; N=32768 tokens, K=1024, C=256.
// dist = |e|^2 - 2 z.e  (|z|^2 argmin-invariant). z.e via 3-pass fp16 split MFMA
// (zh*eh + zh*el + zl*eh, fp32 accum). Tokens with approx top-2 gap <= DELTA get
// exact fp32 rescan (rescue kernel).
//
// d_out doubles as scratch before the epilogue overwrites it:
//   zh plane @ d_out bytes [0, 16777216), zl @ [16777216, 33554432)
// ws layout (bytes):
//   eh      @ 0         _Float16[1024*256]
//   el      @ 524288    _Float16[1024*256]
//   enorm   @ 1048576   float[1024]
//   p1      @ 1052672   u64[32768]   packed (key(min)|idx), atomicMin-merged
//   p2      @ 1314816   u64[32768]   packed second-min
//   idx     @ 1576960   int[32768]
//   counts  @ 1708032   int[1024]
//   lsum    @ 1712128   float
//   nflag   @ 1712192   int
//   flaglist@ 1712256   int[32768]

#define BETA  0.25f
#define DELTA 0.03f

typedef _Float16 half8  __attribute__((ext_vector_type(8)));
typedef _Float16 half4t __attribute__((ext_vector_type(4)));
typedef float    f32x4  __attribute__((ext_vector_type(4)));
typedef unsigned long long u64;

#define GLOAD_LDS16(g, l) \
    __builtin_amdgcn_global_load_lds((const __attribute__((address_space(1))) unsigned int*)(g), \
                                     (__attribute__((address_space(3))) unsigned int*)(l), 16, 0, 0)

__device__ inline u64 packdi(float v, int idx) {
    unsigned int u = __float_as_uint(v);
    unsigned int key = (u & 0x80000000u) ? ~u : (u | 0x80000000u);
    return ((u64)key << 32) | (unsigned int)idx;
}
__device__ inline float unkeyf(unsigned int k) {
    unsigned int u = (k & 0x80000000u) ? (k ^ 0x80000000u) : ~k;
    return __uint_as_float(u);
}

// ---------------------------------------------------------------------------
// Kernel 1: codebook -> eh/el f16 planes + exact |e|^2 + init accumulators.
// grid 256 x 256. wave w of block handles row r = bid*4+w.
// ---------------------------------------------------------------------------
__global__ __launch_bounds__(256) void vq_prep_cb(
    const float* __restrict__ cb, _Float16* __restrict__ eh, _Float16* __restrict__ el,
    float* __restrict__ enorm, u64* __restrict__ p1, u64* __restrict__ p2,
    int* __restrict__ counts, float* __restrict__ lsum, int* __restrict__ nflag)
{
    const int tid = threadIdx.x;
    const int gi  = blockIdx.x * 256 + tid;
    if (gi < 32768) p1[gi] = ~0ull; else p2[gi - 32768] = ~0ull;
    if (blockIdx.x < 4) counts[blockIdx.x * 256 + tid] = 0;
    if (gi == 0) { *lsum = 0.0f; *nflag = 0; }

    const int lane = tid & 63;
    const int r    = blockIdx.x * 4 + (tid >> 6);
    const float4 v = *reinterpret_cast<const float4*>(cb + r * 256 + lane * 4);
    half4t hv, lv;
    hv.x = (_Float16)v.x; lv.x = (_Float16)(v.x - (float)hv.x);
    hv.y = (_Float16)v.y; lv.y = (_Float16)(v.y - (float)hv.y);
    hv.z = (_Float16)v.z; lv.z = (_Float16)(v.z - (float)hv.z);
    hv.w = (_Float16)v.w; lv.w = (_Float16)(v.w - (float)hv.w);
    *reinterpret_cast<half4t*>(eh + r * 256 + lane * 4) = hv;
    *reinterpret_cast<half4t*>(el + r * 256 + lane * 4) = lv;
    float s = v.x * v.x + v.y * v.y + v.z * v.z + v.w * v.w;
    #pragma unroll
    for (int off = 32; off > 0; off >>= 1) s += __shfl_down(s, off);
    if (lane == 0) enorm[r] = s;
}

// ---------------------------------------------------------------------------
// Kernel 2: z [b][c][hw] -> zh/zl f16 planes in token-major [n][c] layout.
// grid 512 (64 tokens each). LDS transpose with register 4x4 sub-transposes so
// both LDS sides use b128 and global sides are coalesced.
// ---------------------------------------------------------------------------
__global__ __launch_bounds__(256) void vq_prep_z(
    const float* __restrict__ z, _Float16* __restrict__ zh, _Float16* __restrict__ zl)
{
    __shared__ float ts[64 * 260];
    const int tid = threadIdx.x;
    const int n0  = blockIdx.x * 64;
    const float* zb = z + (n0 >> 10) * 262144 + (n0 & 1023);

    const int cq = tid >> 4, t4 = (tid & 15) * 4;
    #pragma unroll
    for (int p = 0; p < 4; ++p) {
        const int c0 = p * 64 + cq * 4;
        const float4 v0 = *reinterpret_cast<const float4*>(zb + (c0 + 0) * 1024 + t4);
        const float4 v1 = *reinterpret_cast<const float4*>(zb + (c0 + 1) * 1024 + t4);
        const float4 v2 = *reinterpret_cast<const float4*>(zb + (c0 + 2) * 1024 + t4);
        const float4 v3 = *reinterpret_cast<const float4*>(zb + (c0 + 3) * 1024 + t4);
        float4 w;
        w.x = v0.x; w.y = v1.x; w.z = v2.x; w.w = v3.x;
        *reinterpret_cast<float4*>(&ts[(t4 + 0) * 260 + c0]) = w;
        w.x = v0.y; w.y = v1.y; w.z = v2.y; w.w = v3.y;
        *reinterpret_cast<float4*>(&ts[(t4 + 1) * 260 + c0]) = w;
        w.x = v0.z; w.y = v1.z; w.z = v2.z; w.w = v3.z;
        *reinterpret_cast<float4*>(&ts[(t4 + 2) * 260 + c0]) = w;
        w.x = v0.w; w.y = v1.w; w.z = v2.w; w.w = v3.w;
        *reinterpret_cast<float4*>(&ts[(t4 + 3) * 260 + c0]) = w;
    }
    __syncthreads();
    #pragma unroll
    for (int p = 0; p < 8; ++p) {
        const int row = p * 8 + (tid >> 5);
        const int c0  = (tid & 31) * 8;
        const float4 f0 = *reinterpret_cast<const float4*>(&ts[row * 260 + c0]);
        const float4 f1 = *reinterpret_cast<const float4*>(&ts[row * 260 + c0 + 4]);
        half8 hv, lv;
        hv[0] = (_Float16)f0.x; lv[0] = (_Float16)(f0.x - (float)hv[0]);
        hv[1] = (_Float16)f0.y; lv[1] = (_Float16)(f0.y - (float)hv[1]);
        hv[2] = (_Float16)f0.z; lv[2] = (_Float16)(f0.z - (float)hv[2]);
        hv[3] = (_Float16)f0.w; lv[3] = (_Float16)(f0.w - (float)hv[3]);
        hv[4] = (_Float16)f1.x; lv[4] = (_Float16)(f1.x - (float)hv[4]);
        hv[5] = (_Float16)f1.y; lv[5] = (_Float16)(f1.y - (float)hv[5]);
        hv[6] = (_Float16)f1.z; lv[6] = (_Float16)(f1.z - (float)hv[6]);
        hv[7] = (_Float16)f1.w; lv[7] = (_Float16)(f1.w - (float)hv[7]);
        *reinterpret_cast<half8*>(zh + (size_t)(n0 + row) * 256 + c0) = hv;
        *reinterpret_cast<half8*>(zl + (size_t)(n0 + row) * 256 + c0) = lv;
    }
}

// ---------------------------------------------------------------------------
// Kernel 3: MFMA distance GEMM + per-block top-2 argmin, merged globally via
// packed atomicMin. grid (256 token-tiles, 8 code-tiles), 128x128 per block,
// 4 waves of 64x64, 16x16x32 f16 MFMA, 3 split passes into one fp32 acc.
// ---------------------------------------------------------------------------
__global__ __launch_bounds__(256) void vq_mfma(
    const _Float16* __restrict__ zh, const _Float16* __restrict__ zl,
    const _Float16* __restrict__ eh, const _Float16* __restrict__ el,
    const float* __restrict__ enorm, u64* __restrict__ p1, u64* __restrict__ p2)
{
    __shared__ _Float16 sAh[128 * 32], sAl[128 * 32], sBh[128 * 32], sBl[128 * 32];
    __shared__ float lm1[2][128], lm2[2][128];
    __shared__ int   li1[2][128];

    const int tid  = threadIdx.x;
    const int lane = tid & 63;
    const int wv   = tid >> 6;
    const int wm   = wv >> 1, wn = wv & 1;
    const int n0   = blockIdx.x * 128;   // tokens
    const int k0   = blockIdx.y * 128;   // codes

    // staging: chunk ch covers row=ch>>2, 8 halves at q=ch&3. ch1=tid, ch2=tid+256.
    const int row1 = tid >> 2, q1 = tid & 3;
    const _Float16* gAh1 = zh + (size_t)(n0 + row1) * 256 + q1 * 8;
    const _Float16* gAh2 = zh + (size_t)(n0 + row1 + 64) * 256 + q1 * 8;
    const _Float16* gAl1 = zl + (size_t)(n0 + row1) * 256 + q1 * 8;
    const _Float16* gAl2 = zl + (size_t)(n0 + row1 + 64) * 256 + q1 * 8;
    const _Float16* gBh1 = eh + (size_t)(k0 + row1) * 256 + q1 * 8;
    const _Float16* gBh2 = eh + (size_t)(k0 + row1 + 64) * 256 + q1 * 8;
    const _Float16* gBl1 = el + (size_t)(k0 + row1) * 256 + q1 * 8;
    const _Float16* gBl2 = el + (size_t)(k0 + row1 + 64) * 256 + q1 * 8;

    const int abase = (wm * 64 + (lane & 15)) * 32 + (lane >> 4) * 8;
    const int bbase = (wn * 64 + (lane & 15)) * 32 + (lane >> 4) * 8;

    f32x4 acc[4][4] = {};

    for (int kc = 0; kc < 8; ++kc) {
        const int co = kc * 32;
        GLOAD_LDS16(gAh1 + co, &sAh[tid * 8]);
        GLOAD_LDS16(gAh2 + co, &sAh[(tid + 256) * 8]);
        GLOAD_LDS16(gAl1 + co, &sAl[tid * 8]);
        GLOAD_LDS16(gAl2 + co, &sAl[(tid + 256) * 8]);
        GLOAD_LDS16(gBh1 + co, &sBh[tid * 8]);
        GLOAD_LDS16(gBh2 + co, &sBh[(tid + 256) * 8]);
        GLOAD_LDS16(gBl1 + co, &sBl[tid * 8]);
        GLOAD_LDS16(gBl2 + co, &sBl[(tid + 256) * 8]);
        __syncthreads();

        half8 ah[4], al[4], bh[4], bl[4];
        #pragma unroll
        for (int mt = 0; mt < 4; ++mt) {
            ah[mt] = *reinterpret_cast<const half8*>(&sAh[abase + mt * 512]);
            al[mt] = *reinterpret_cast<const half8*>(&sAl[abase + mt * 512]);
        }
        #pragma unroll
        for (int nt = 0; nt < 4; ++nt) {
            bh[nt] = *reinterpret_cast<const half8*>(&sBh[bbase + nt * 512]);
            bl[nt] = *reinterpret_cast<const half8*>(&sBl[bbase + nt * 512]);
        }
        #pragma unroll
        for (int mt = 0; mt < 4; ++mt)
            #pragma unroll
            for (int nt = 0; nt < 4; ++nt) {
                acc[mt][nt] = __builtin_amdgcn_mfma_f32_16x16x32_f16(ah[mt], bh[nt], acc[mt][nt], 0, 0, 0);
                acc[mt][nt] = __builtin_amdgcn_mfma_f32_16x16x32_f16(ah[mt], bl[nt], acc[mt][nt], 0, 0, 0);
                acc[mt][nt] = __builtin_amdgcn_mfma_f32_16x16x32_f16(al[mt], bh[nt], acc[mt][nt], 0, 0, 0);
            }
        __syncthreads();
    }

    // epilogue: dist = enorm - 2*dot; per-token top-2 over this wave's 64 codes.
    // D layout: row(m)=(lane>>4)*4+reg, col(n)=lane&15  [m89-verified]
    const int cbase = k0 + wn * 64 + (lane & 15);
    float en_v[4];
    #pragma unroll
    for (int nt = 0; nt < 4; ++nt) en_v[nt] = enorm[cbase + nt * 16];

    #pragma unroll
    for (int mt = 0; mt < 4; ++mt) {
        #pragma unroll
        for (int reg = 0; reg < 4; ++reg) {
            const int tloc = wm * 64 + mt * 16 + (lane >> 4) * 4 + reg;
            float m1 = 1e30f, m2 = 1e30f; int i1 = 0x7fffffff;
            #pragma unroll
            for (int nt = 0; nt < 4; ++nt) {   // ascending code order
                const float d = fmaf(-2.0f, acc[mt][nt][reg], en_v[nt]);
                if (d < m1) { m2 = m1; m1 = d; i1 = cbase + nt * 16; }
                else        { m2 = fminf(m2, d); }
            }
            #pragma unroll
            for (int off = 1; off < 16; off <<= 1) {
                const float om1 = __shfl_xor(m1, off);
                const int   oi1 = __shfl_xor(i1, off);
                const float om2 = __shfl_xor(m2, off);
                if (om1 < m1 || (om1 == m1 && oi1 < i1)) { m2 = fminf(m1, om2); m1 = om1; i1 = oi1; }
                else                                     { m2 = fminf(m2, om1); }
            }
            if ((lane & 15) == 0) { lm1[wn][tloc] = m1; li1[wn][tloc] = i1; lm2[wn][tloc] = m2; }
        }
    }
    __syncthreads();
    if (tid < 128) {
        const float a1 = lm1[0][tid], a2 = lm2[0][tid];
        const int   ai = li1[0][tid];
        const float b1 = lm1[1][tid], b2 = lm2[1][tid];
        const int   bi = li1[1][tid];
        float m1, m2; int i1;
        if (b1 < a1 || (b1 == a1 && bi < ai)) { m1 = b1; i1 = bi; m2 = fminf(a1, b2); }
        else                                  { m1 = a1; i1 = ai; m2 = fminf(a2, b1); }
        const int n = n0 + tid;
        const u64 me1 = packdi(m1, i1);
        const u64 me2 = packdi(m2, 0x7fffffff);
        const u64 old = atomicMin(&p1[n], me1);
        const u64 loser = old > me1 ? old : me1;
        atomicMin(&p2[n], loser < me2 ? loser : me2);
    }
}

// ---------------------------------------------------------------------------
// Kernel 4: unpack global top-2 -> idx; flag ambiguous tokens (gap <= DELTA).
// ---------------------------------------------------------------------------
__global__ __launch_bounds__(256) void vq_reduce_flag(
    const u64* __restrict__ p1, const u64* __restrict__ p2,
    int* __restrict__ idx, int* __restrict__ nflag, int* __restrict__ flaglist)
{
    const int n = blockIdx.x * 256 + threadIdx.x;
    const u64 a = p1[n], b = p2[n];
    const int i1 = (int)(a & 0xffffffffu);
    idx[n] = i1;
    const float v1 = unkeyf((unsigned int)(a >> 32));
    const float v2 = unkeyf((unsigned int)(b >> 32));
    if (v2 - v1 <= DELTA) {
        const int p = atomicAdd(nflag, 1);
        flaglist[p] = n;
    }
}

// ---------------------------------------------------------------------------
// Kernel 5: exact fp32 rescan for flagged tokens. grid 64 fixed (graph-safe);
// per token: all 1024 codes, 4/thread, block argmin with first-occurrence ties.
// ---------------------------------------------------------------------------
__global__ __launch_bounds__(256) void vq_rescue(
    const float* __restrict__ z, const float* __restrict__ cb,
    const float* __restrict__ enorm, const int* __restrict__ nflag,
    const int* __restrict__ flaglist, int* __restrict__ idx)
{
    __shared__ float zs[256];
    __shared__ float rv[256];
    __shared__ int   ri[256];
    const int tid = threadIdx.x;
    const int count = *nflag;
    for (int i = blockIdx.x; i < count; i += 64) {
        const int n = flaglist[i];
        zs[tid] = z[(n >> 10) * 262144 + tid * 1024 + (n & 1023)];
        __syncthreads();
        float bv = 1e30f; int bi = 0x7fffffff;
        #pragma unroll
        for (int j = 0; j < 4; ++j) {
            const int k = tid * 4 + j;
            const float* er = cb + k * 256;
            float s = 0.0f;
            for (int c = 0; c < 256; c += 4) {
                const float4 e4 = *reinterpret_cast<const float4*>(er + c);
                s = fmaf(e4.x, zs[c], s);
                s = fmaf(e4.y, zs[c + 1], s);
                s = fmaf(e4.z, zs[c + 2], s);
                s = fmaf(e4.w, zs[c + 3], s);
            }
            const float d = fmaf(-2.0f, s, enorm[k]);
            if (d < bv) { bv = d; bi = k; }
        }
        rv[tid] = bv; ri[tid] = bi;
        __syncthreads();
        for (int s = 128; s > 0; s >>= 1) {
            if (tid < s) {
                const float ov = rv[tid + s]; const int oi = ri[tid + s];
                if (ov < rv[tid] || (ov == rv[tid] && oi < ri[tid])) { rv[tid] = ov; ri[tid] = oi; }
            }
            __syncthreads();
        }
        if (tid == 0) idx[n] = ri[0];
        __syncthreads();
    }
}

// ---------------------------------------------------------------------------
// Kernel 6: gather z_q -> out, fused sum((z_q-z)^2) + histogram. (round-0, passed)
// ---------------------------------------------------------------------------
__global__ __launch_bounds__(256) void vq_epilogue(
    const float* __restrict__ z, const float* __restrict__ cb,
    const int* __restrict__ idx, float* __restrict__ out,
    int* __restrict__ counts, float* __restrict__ lsum)
{
    __shared__ int   sidx[64];
    __shared__ float swsum[4];
    const int tid = threadIdx.x;
    const int n0  = blockIdx.x * 64;
    if (tid < 64) {
        const int ii = idx[n0 + tid];
        sidx[tid] = ii;
        atomicAdd(&counts[ii], 1);
    }
    __syncthreads();
    const float* zb = z   + (n0 >> 10) * 262144 + (n0 & 1023);
    float*       ob = out + (n0 >> 10) * 262144 + (n0 & 1023);
    const int t  = tid & 63;
    const int cg = tid >> 6;
    const int row = sidx[t] << 8;
    float sum = 0.0f;
    for (int c = cg; c < 256; c += 4) {
        const float q  = cb[row + c];
        const float zv = zb[c * 1024 + t];
        const float d  = q - zv;
        sum = fmaf(d, d, sum);
        ob[c * 1024 + t] = q;
    }
    #pragma unroll
    for (int off = 32; off > 0; off >>= 1) sum += __shfl_down(sum, off);
    if ((tid & 63) == 0) swsum[tid >> 6] = sum;
    __syncthreads();
    if (tid == 0) atomicAdd(lsum, swsum[0] + swsum[1] + swsum[2] + swsum[3]);
}

// ---------------------------------------------------------------------------
// Kernel 7: scalars. (round-0, passed)
// ---------------------------------------------------------------------------
__global__ __launch_bounds__(256) void vq_finalize(
    const int* __restrict__ counts, const float* __restrict__ lsum,
    float* __restrict__ outs)
{
    __shared__ float ssum[4];
    const int tid = threadIdx.x;
    float local = 0.0f;
    #pragma unroll
    for (int k = tid; k < 1024; k += 256) {
        float p = (float)counts[k] * (1.0f / 32768.0f);
        p = fmaxf(p, 1e-10f);
        local += p * logf(p);
    }
    #pragma unroll
    for (int off = 32; off > 0; off >>= 1) local += __shfl_down(local, off);
    if ((tid & 63) == 0) ssum[tid >> 6] = local;
    __syncthreads();
    if (tid == 0) {
        const float ent = ssum[0] + ssum[1] + ssum[2] + ssum[3];
        outs[0] = lsum[0] * ((1.0f + BETA) / 8388608.0f);
        outs[1] = expf(-ent);
    }
}

extern "C" void kernel_launch(void* const* d_in, const int* in_sizes, int n_in,
                              void* d_out, int out_size, void* d_ws, size_t ws_size,
                              hipStream_t stream)
{
    const float* z  = (const float*)d_in[0];
    const float* cb = (const float*)d_in[1];
    float* out = (float*)d_out;

    _Float16* zh = (_Float16*)d_out;                 // scratch-in-out: overwritten by epilogue
    _Float16* zl = (_Float16*)d_out + 8388608;

    char* ws = (char*)d_ws;
    _Float16* eh     = (_Float16*)(ws);
    _Float16* el     = (_Float16*)(ws + 524288);
    float*    enorm  = (float*)   (ws + 1048576);
    u64*      p1     = (u64*)     (ws + 1052672);
    u64*      p2     = (u64*)     (ws + 1314816);
    int*      idx    = (int*)     (ws + 1576960);
    int*      counts = (int*)     (ws + 1708032);
    float*    lsum   = (float*)   (ws + 1712128);
    int*      nflag  = (int*)     (ws + 1712192);
    int*      flag   = (int*)     (ws + 1712256);

    vq_prep_cb    <<<256, 256, 0, stream>>>(cb, eh, el, enorm, p1, p2, counts, lsum, nflag);
    vq_prep_z     <<<512, 256, 0, stream>>>(z, zh, zl);
    vq_mfma       <<<dim3(256, 8), 256, 0, stream>>>(zh, zl, eh, el, enorm, p1, p2);
    vq_reduce_flag<<<128, 256, 0, stream>>>(p1, p2, idx, nflag, flag);
    vq_rescue     <<<64, 256, 0, stream>>>(z, cb, enorm, nflag, flag, idx);
    vq_epilogue   <<<512, 256, 0, stream>>>(z, cb, idx, out, counts, lsum);
    vq_finalize   <<<1, 256, 0, stream>>>(counts, lsum, out + 8388608);
}